// Round 7
// baseline (272.685 us; speedup 1.0000x reference)
//
#include <hip/hip_runtime.h>

// ConvTranspose2d(64->64, k=3, s=2, p=1, out_pad=1) + bias + clip(0, 0.5)
// x: (32,64,128,128) f32, w: (64ci,64co,3,3) f32, b: (64) f32 -> out: (32,64,256,256) f32
//
// MFMA path (fragment conventions verified rounds 5-6): parity decomposition into
// 9 taps; per tap a GEMM over ci with mfma_f32_32x32x16_bf16, A = w-frag (rows=co),
// B = x-frag (cols=pixel). Split-bf16 (hi/lo) 3-product accumulation.
//
// Round-7 change (structure only, numerics identical):
//  - single-stage LDS: whole 3x33x64ci tile (hi+lo) staged ONCE (25.3 KB), ONE barrier,
//    then 108 MFMA per wave straight-line (no per-ks barriers, no double buffer)
//  - XOR-swizzled LDS (16B chunk ^= j&7): conflict-free ds_read_b128 fragments
//  - 4 blocks/CU (16 waves) via __launch_bounds__(256,4)

#define CIN 64
#define COUT 64
#define HI 128
#define WI 128
#define HO 256
#define WO 256
#define HW (HI*WI)

typedef __attribute__((ext_vector_type(8))) short short8;
typedef __attribute__((ext_vector_type(16))) float f32x16;

__device__ __forceinline__ unsigned short f2bf(float f) {
    unsigned int u = __float_as_uint(f);
    unsigned int r = u + 0x7FFFu + ((u >> 16) & 1u);
    return (unsigned short)(r >> 16);
}
__device__ __forceinline__ float bf2f(unsigned short h) {
    return __uint_as_float(((unsigned int)h) << 16);
}

// ---- prep: wfrag[frag=((tap*4+ks)*2+ct)*2+hl][lane64][j8] ushort (bf16) ----
// (unchanged from rounds 5-6, verified)
__global__ void prep_wfrag(const float* __restrict__ w, unsigned short* __restrict__ wf) {
    int idx = blockIdx.x * 256 + threadIdx.x;
    if (idx >= 144 * 64) return;
    int lane = idx & 63;
    int frag = idx >> 6;
    int hl  = frag & 1;
    int ct  = (frag >> 1) & 1;
    int ks  = (frag >> 2) & 3;
    int tap = frag >> 4;
    int co  = ct * 32 + (lane & 31);
    unsigned int packed[4];
    #pragma unroll
    for (int jp = 0; jp < 4; ++jp) {
        unsigned short h2[2];
        #pragma unroll
        for (int e = 0; e < 2; ++e) {
            int j = jp * 2 + e;
            int ci = ks * 16 + (lane >> 5) * 8 + j;
            float v = w[(ci * COUT + co) * 9 + tap];
            unsigned short h = f2bf(v);
            if (hl) h = f2bf(v - bf2f(h));
            h2[e] = h;
        }
        packed[jp] = (unsigned)h2[0] | ((unsigned)h2[1] << 16);
    }
    ((uint4*)wf)[idx] = make_uint4(packed[0], packed[1], packed[2], packed[3]);
}

// ---- LDS: [hl][row3][j33][ci64] ushort, 16B chunks XOR-swizzled by (j&7) ----
#define S_ROWB 4224          // 33 * 128 B
#define S_HLB  (3*S_ROWB)    // 12672 B
#define S_TOTB (2*S_HLB)     // 25344 B

__device__ __forceinline__ int lds_byte(int hl, int row, int j, int ci) {
    int chunk = (ci >> 3) ^ (j & 7);          // 8 chunks of 16B per (row,j)
    return hl * S_HLB + row * S_ROWB + j * 128 + chunk * 16 + (ci & 7) * 2;
}

__global__ __launch_bounds__(256, 4) void convt_mfma_kernel(
    const float* __restrict__ x,
    const unsigned short* __restrict__ wf,
    const float* __restrict__ bias,
    float* __restrict__ out)
{
    __shared__ __align__(16) unsigned char lds[S_TOTB];

    const int n    = blockIdx.z;
    const int i_in = blockIdx.y * 2;    // rows i_in..i_in+2 (2 owned + 1 halo)
    const int j0   = blockIdx.x * 32;   // cols j0..j0+32 (32 owned + 1 halo)

    const int tid = threadIdx.x;
    const int l   = tid & 63;
    const int wid = tid >> 6;
    const int ct  = wid & 1;            // co tile (32 co per wave)
    const int rp  = wid >> 1;           // owned input row within block (0,1)

    const float* xn = x + (size_t)n * CIN * HW;

    // ---- stage ENTIRE x tile once: 3 rows * 33 j * 16 ci-quads = 1584 items ----
    #pragma unroll
    for (int base = 0; base < 1584; base += 256) {
        int f = base + tid;
        if (f < 1584) {
            int row = f / 528;
            int rem = f - row * 528;
            int cq  = rem / 33;
            int j   = rem - cq * 33;
            int gi = i_in + row, gj = j0 + j;
            float v0 = 0.f, v1 = 0.f, v2 = 0.f, v3 = 0.f;
            if (gi < HI && gj < WI) {
                const float* s = xn + ((size_t)(cq * 4) * HI + gi) * WI + gj;
                v0 = s[0]; v1 = s[HW]; v2 = s[2 * HW]; v3 = s[3 * HW];
            }
            unsigned short h0 = f2bf(v0), h1 = f2bf(v1), h2 = f2bf(v2), h3 = f2bf(v3);
            unsigned short g0 = f2bf(v0 - bf2f(h0)), g1 = f2bf(v1 - bf2f(h1));
            unsigned short g2 = f2bf(v2 - bf2f(h2)), g3 = f2bf(v3 - bf2f(h3));
            *(uint2*)&lds[lds_byte(0, row, j, cq * 4)] =
                make_uint2((unsigned)h0 | ((unsigned)h1 << 16),
                           (unsigned)h2 | ((unsigned)h3 << 16));
            *(uint2*)&lds[lds_byte(1, row, j, cq * 4)] =
                make_uint2((unsigned)g0 | ((unsigned)g1 << 16),
                           (unsigned)g2 | ((unsigned)g3 << 16));
        }
    }

    f32x16 acc[2][2];   // [dh][dw] for this wave's ct
    #pragma unroll
    for (int a = 0; a < 2; ++a)
        #pragma unroll
        for (int b = 0; b < 2; ++b)
            #pragma unroll
            for (int e = 0; e < 16; ++e) acc[a][b][e] = 0.0f;

    __syncthreads();   // the ONLY barrier

    // ---- straight-line compute: 4 ks * (4 xf-groups, 9 taps) * 3 MFMA ----
    const unsigned short* wkb = wf + (size_t)ct * 1024 + (size_t)l * 8;
    const int jj = l & 31;
    const int ch = (l >> 5);   // ci-half selector

    #define DO_TAP(t, dh, dw)                                                        \
        {                                                                            \
            short8 wh = *(const short8*)&wkb[(t) * 8192 + ks * 2048];                \
            short8 wl = *(const short8*)&wkb[(t) * 8192 + ks * 2048 + 512];          \
            f32x16 a = acc[dh][dw];                                                  \
            a = __builtin_amdgcn_mfma_f32_32x32x16_bf16(wh, xh, a, 0, 0, 0);         \
            a = __builtin_amdgcn_mfma_f32_32x32x16_bf16(wh, xl, a, 0, 0, 0);         \
            a = __builtin_amdgcn_mfma_f32_32x32x16_bf16(wl, xh, a, 0, 0, 0);         \
            acc[dh][dw] = a;                                                         \
        }
    #define LOAD_XF(r, s)                                                            \
        short8 xh, xl;                                                               \
        {                                                                            \
            int ci0 = ks * 16 + ch * 8;                                              \
            xh = *(const short8*)&lds[lds_byte(0, rp + (r), jj + (s), ci0)];         \
            xl = *(const short8*)&lds[lds_byte(1, rp + (r), jj + (s), ci0)];         \
        }

    #pragma unroll
    for (int ks = 0; ks < 4; ++ks) {
        { LOAD_XF(1, 1) DO_TAP(0, 1, 1) }                                   // t0
        { LOAD_XF(1, 0) DO_TAP(1, 1, 0) DO_TAP(2, 1, 1) }                   // t1,t2
        { LOAD_XF(0, 1) DO_TAP(3, 0, 1) DO_TAP(6, 1, 1) }                   // t3,t6
        { LOAD_XF(0, 0) DO_TAP(4, 0, 0) DO_TAP(5, 0, 1)
                        DO_TAP(7, 1, 0) DO_TAP(8, 1, 1) }                   // t4,5,7,8
    }
    #undef DO_TAP
    #undef LOAD_XF

    // ---- epilogue: bias + clamp; lane = pixel -> coalesced dwordx2 stores ----
    float bco[16];
    #pragma unroll
    for (int rg = 0; rg < 16; ++rg)
        bco[rg] = bias[ct * 32 + (rg & 3) + 8 * (rg >> 2) + 4 * ch];

    float* outn = out + (size_t)n * COUT * HO * WO;
    const int ow0 = 2 * (j0 + jj);
    #pragma unroll
    for (int dh = 0; dh < 2; ++dh) {
        const int oh = 2 * (i_in + rp) + dh;
        #pragma unroll
        for (int rg = 0; rg < 16; ++rg) {
            const int co = ct * 32 + (rg & 3) + 8 * (rg >> 2) + 4 * ch;
            float v0 = acc[dh][0][rg] + bco[rg];
            float v1 = acc[dh][1][rg] + bco[rg];
            v0 = fminf(fmaxf(v0, 0.f), 0.5f);
            v1 = fminf(fmaxf(v1, 0.f), 0.5f);
            *(float2*)&outn[((size_t)co * HO + oh) * WO + ow0] = make_float2(v0, v1);
        }
    }
}

// ---------------- fallback (no-workspace): fp32 VALU kernel ----------------
#define TILE_I 4
#define TILE_J 16
#define HALO_I (TILE_I + 1)
#define HALO_J (TILE_J + 1)
#define XS_CSTRIDE 20
#define XS_RSTRIDE (HALO_I * XS_CSTRIDE)
#define XS_FLOATS (CIN * XS_RSTRIDE)

struct Regs { float wk[9]; float xa[2][HALO_J]; };

__device__ __forceinline__ void load_ci_fb(int ci, const float* __restrict__ wsrc,
                                           const float* xs, int warp, int lane, Regs& R) {
    #pragma unroll
    for (int k = 0; k < 9; ++k) R.wk[k] = wsrc[(ci * COUT + lane) * 9 + k];
    const float* xr = xs + ci * XS_RSTRIDE + warp * XS_CSTRIDE;
    #pragma unroll
    for (int rr = 0; rr < 2; ++rr) {
        const float4* p4 = reinterpret_cast<const float4*>(xr + rr * XS_CSTRIDE);
        #pragma unroll
        for (int q = 0; q < 4; ++q) {
            float4 v = p4[q];
            R.xa[rr][4*q+0] = v.x; R.xa[rr][4*q+1] = v.y;
            R.xa[rr][4*q+2] = v.z; R.xa[rr][4*q+3] = v.w;
        }
        R.xa[rr][16] = xr[rr * XS_CSTRIDE + 16];
    }
}

__device__ __forceinline__ void do_fma_fb(const Regs& R, float (&acc)[TILE_J][4]) {
    #pragma unroll
    for (int p = 0; p < TILE_J; ++p) {
        const float x00 = R.xa[0][p], x01 = R.xa[0][p+1];
        const float x10 = R.xa[1][p], x11 = R.xa[1][p+1];
        acc[p][0] += x00 * R.wk[4];
        acc[p][1] += x00 * R.wk[5]; acc[p][1] += x01 * R.wk[3];
        acc[p][2] += x00 * R.wk[7]; acc[p][2] += x10 * R.wk[1];
        acc[p][3] += x00 * R.wk[8]; acc[p][3] += x01 * R.wk[6];
        acc[p][3] += x10 * R.wk[2]; acc[p][3] += x11 * R.wk[0];
    }
}

__device__ __forceinline__ int es_slot_fb(int co, int oh, int g) {
    return co * 64 + oh * 8 + (g ^ (co & 7) ^ oh);
}

__global__ __launch_bounds__(256, 2) void convt_fallback_kernel(
    const float* __restrict__ x, const float* __restrict__ wsrc,
    const float* __restrict__ bias, float* __restrict__ out) {
    __shared__ __align__(16) float xs[XS_FLOATS];
    const int n = blockIdx.z, i0 = blockIdx.y * TILE_I, j0 = blockIdx.x * TILE_J;
    const float* xnf = x + (size_t)n * CIN * HI * WI;
    for (int f = threadIdx.x; f < CIN * HALO_I * HALO_J; f += 256) {
        int ci = f / (HALO_I * HALO_J);
        int rem = f - ci * (HALO_I * HALO_J);
        int r = rem / HALO_J, c = rem - r * HALO_J;
        int gi = i0 + r, gj = j0 + c;
        float v = 0.0f;
        if (gi < HI && gj < WI) v = xnf[(ci * HI + gi) * WI + gj];
        xs[ci * XS_RSTRIDE + r * XS_CSTRIDE + c] = v;
    }
    __syncthreads();
    const int warp = threadIdx.x >> 6, lane = threadIdx.x & 63;
    const float bcf = bias[lane];
    float acc[TILE_J][4];
    #pragma unroll
    for (int p = 0; p < TILE_J; ++p)
        #pragma unroll
        for (int q = 0; q < 4; ++q) acc[p][q] = 0.0f;
    Regs A, B1;
    load_ci_fb(0, wsrc, xs, warp, lane, A);
    #pragma unroll 1
    for (int ci = 0; ci < CIN; ci += 2) {
        load_ci_fb(ci + 1, wsrc, xs, warp, lane, B1);
        do_fma_fb(A, acc);
        int cin = (ci + 2 < CIN) ? ci + 2 : CIN - 1;
        load_ci_fb(cin, wsrc, xs, warp, lane, A);
        do_fma_fb(B1, acc);
    }
    float* outn = out + (size_t)n * COUT * HO * WO;
    const int ohb = 2 * i0, owb = 2 * j0;
    __syncthreads();
    float* es = xs;
    #pragma unroll 1
    for (int chunk = 0; chunk < 4; ++chunk) {
        const int c0 = chunk * 16;
        if ((lane & 48) == c0) {
            const int col = lane & 15;
            #pragma unroll
            for (int p = 0; p < TILE_J; ++p)
                #pragma unroll
                for (int q = 0; q < 4; ++q) {
                    const int ohl = warp * 2 + (q >> 1);
                    const int ow = 2 * p + (q & 1);
                    float v = acc[p][q] + bcf;
                    v = fminf(fmaxf(v, 0.0f), 0.5f);
                    es[es_slot_fb(col, ohl, ow >> 2) * 4 + (ow & 3)] = v;
                }
        }
        __syncthreads();
        {
            const int co_l = threadIdx.x >> 4;
            const int oh_l = (threadIdx.x & 15) >> 1;
            const int half = threadIdx.x & 1;
            float* dst = &outn[((size_t)(c0 + co_l) * HO + (ohb + oh_l)) * WO + owb + half * 16];
            #pragma unroll
            for (int qq = 0; qq < 4; ++qq) {
                const int g = half * 4 + qq;
                float4 v = *reinterpret_cast<const float4*>(&es[es_slot_fb(co_l, oh_l, g) * 4]);
                *reinterpret_cast<float4*>(dst + qq * 4) = v;
            }
        }
        __syncthreads();
    }
}

extern "C" void kernel_launch(void* const* d_in, const int* in_sizes, int n_in,
                              void* d_out, int out_size, void* d_ws, size_t ws_size,
                              hipStream_t stream) {
    const float* x = (const float*)d_in[0];
    const float* w = (const float*)d_in[1];
    const float* b = (const float*)d_in[2];
    float* out = (float*)d_out;
    const int B = in_sizes[0] / (CIN * HI * WI);  // 32

    const size_t wf_bytes = (size_t)144 * 64 * 8 * sizeof(unsigned short); // 147456
    if (ws_size >= wf_bytes) {
        unsigned short* wfrag = (unsigned short*)d_ws;
        prep_wfrag<<<36, 256, 0, stream>>>(w, wfrag);
        dim3 grid(WI / 32, HI / 2, B);            // (4, 64, 32)
        convt_mfma_kernel<<<grid, 256, 0, stream>>>(x, wfrag, b, out);
    } else {
        dim3 grid(WI / TILE_J, HI / TILE_I, B);   // (8, 32, 32)
        convt_fallback_kernel<<<grid, 256, 0, stream>>>(x, w, b, out);
    }
}

// Round 8
// 204.910 us; speedup vs baseline: 1.3308x; 1.3308x over previous
//
#include <hip/hip_runtime.h>

// ConvTranspose2d(64->64, k=3, s=2, p=1, out_pad=1) + bias + clip(0, 0.5)
// x: (32,64,128,128) f32, w: (64ci,64co,3,3) f32, b: (64) f32 -> out: (32,64,256,256) f32
//
// MFMA path: 9-tap parity decomposition, mfma_f32_32x32x16_f16, A=w-frag (rows=co),
// B=x-frag (cols=pixel).  Round-8 numerics: x split hi/lo f16 (x exact to ~2^-21),
// w single RTN f16 -> 2 MFMA products per 16-ci (was 3 with bf16 split).
// Round-8 structure: per-ks weight fragments preloaded to REGISTERS BEFORE the
// stage prefetch loads (vmcnt is ordered: this keeps stage loads in flight across
// the MFMA burst), double-buffered LDS, one barrier per ks.

#define CIN 64
#define COUT 64
#define HI 128
#define WI 128
#define HO 256
#define WO 256
#define HW (HI*WI)

typedef __attribute__((ext_vector_type(8))) _Float16 half8;
typedef __attribute__((ext_vector_type(16))) float f32x16;

__device__ __forceinline__ unsigned short f2h(float v) {
    _Float16 h = (_Float16)v;                       // v_cvt_f16_f32 (RTN)
    return __builtin_bit_cast(unsigned short, h);
}
__device__ __forceinline__ float h2f(unsigned short u) {
    return (float)__builtin_bit_cast(_Float16, u);
}

// ---- prep: wfrag[frag=(tap*4+ks)*2+ct][lane64][j8] f16 ----
// frag element: ci = ks*16 + (lane>>5)*8 + j ; co = ct*32 + (lane&31)
__global__ void prep_wfrag(const float* __restrict__ w, unsigned short* __restrict__ wf) {
    int idx = blockIdx.x * 256 + threadIdx.x;
    if (idx >= 72 * 64) return;
    int lane = idx & 63;
    int frag = idx >> 6;
    int ct  = frag & 1;
    int ks  = (frag >> 1) & 3;
    int tap = frag >> 3;
    int co  = ct * 32 + (lane & 31);
    unsigned int packed[4];
    #pragma unroll
    for (int jp = 0; jp < 4; ++jp) {
        unsigned short h2[2];
        #pragma unroll
        for (int e = 0; e < 2; ++e) {
            int j = jp * 2 + e;
            int ci = ks * 16 + (lane >> 5) * 8 + j;
            h2[e] = f2h(w[(ci * COUT + co) * 9 + tap]);
        }
        packed[jp] = (unsigned)h2[0] | ((unsigned)h2[1] << 16);
    }
    ((uint4*)wf)[idx] = make_uint4(packed[0], packed[1], packed[2], packed[3]);
}

// ---- LDS f16: [buf2][hl2][row3][j33][ci16] ushort ----
#define L_JST 16
#define L_ROW (33*L_JST)    // 528
#define L_HL  (3*L_ROW)     // 1584
#define L_BUF (2*L_HL)      // 3168
#define L_TOT (2*L_BUF)     // 6336 ushorts = 12672 B

__global__ __launch_bounds__(256, 3) void convt_mfma_kernel(
    const float* __restrict__ x,
    const unsigned short* __restrict__ wf,
    const float* __restrict__ bias,
    float* __restrict__ out)
{
    __shared__ __align__(16) unsigned short lds[L_TOT];

    const int n    = blockIdx.z;
    const int i_in = blockIdx.y * 2;    // rows i_in..i_in+2 (2 owned + 1 halo)
    const int j0   = blockIdx.x * 32;   // cols j0..j0+32 (32 owned + 1 halo)

    const int tid = threadIdx.x;
    const int l   = tid & 63;
    const int wid = tid >> 6;
    const int ct  = wid & 1;            // co tile (32 co per wave)
    const int rp  = wid >> 1;           // owned input row within block (0,1)
    const int jj  = l & 31;
    const int ch  = l >> 5;             // ci-half selector

    const float* xn = x + (size_t)n * CIN * HW;

    // ---- staging: 3 rows * 33 j * 4 ci-quads = 396 items; cq fastest for
    //      conflict-free contiguous ds_writes ----
    float sv[2][4];
    int   soff[2];

    auto stage_load = [&](int ks) {
        #pragma unroll
        for (int it = 0; it < 2; ++it) {
            int q = tid + it * 256;
            soff[it] = -1;
            if (q < 396) {
                int cq  = q & 3;
                int p   = q >> 2;        // 0..98
                int j   = p % 33;
                int row = p / 33;
                soff[it] = row * L_ROW + j * L_JST + cq * 4;
                int gi = i_in + row, gj = j0 + j;
                float v0 = 0.f, v1 = 0.f, v2 = 0.f, v3 = 0.f;
                if (gi < HI && gj < WI) {
                    const float* s = xn + ((size_t)(ks * 16 + cq * 4) * HI + gi) * WI + gj;
                    v0 = s[0]; v1 = s[HW]; v2 = s[2 * HW]; v3 = s[3 * HW];
                }
                sv[it][0] = v0; sv[it][1] = v1; sv[it][2] = v2; sv[it][3] = v3;
            }
        }
    };
    auto stage_write = [&](int buf) {
        #pragma unroll
        for (int it = 0; it < 2; ++it) {
            if (soff[it] >= 0) {
                unsigned short h[4], g[4];
                #pragma unroll
                for (int c = 0; c < 4; ++c) {
                    h[c] = f2h(sv[it][c]);
                    g[c] = f2h(sv[it][c] - h2f(h[c]));
                }
                int base = buf * L_BUF + soff[it];
                *(uint2*)&lds[base]        = make_uint2((unsigned)h[0] | ((unsigned)h[1] << 16),
                                                        (unsigned)h[2] | ((unsigned)h[3] << 16));
                *(uint2*)&lds[base + L_HL] = make_uint2((unsigned)g[0] | ((unsigned)g[1] << 16),
                                                        (unsigned)g[2] | ((unsigned)g[3] << 16));
            }
        }
    };

    f32x16 acc[2][2];   // [dh][dw]
    #pragma unroll
    for (int a = 0; a < 2; ++a)
        #pragma unroll
        for (int b = 0; b < 2; ++b)
            #pragma unroll
            for (int e = 0; e < 16; ++e) acc[a][b][e] = 0.0f;

    stage_load(0);
    stage_write(0);
    __syncthreads();

    #pragma unroll 1
    for (int ks = 0; ks < 4; ++ks) {
        const int buf = ks & 1;

        // (1) weight fragments -> registers FIRST (so their vmcnt wait does not
        //     drain the stage prefetch issued below)
        half8 wr[9];
        #pragma unroll
        for (int t = 0; t < 9; ++t)
            wr[t] = *(const half8*)&wf[(size_t)(((t * 4 + ks) * 2 + ct) * 512) + l * 8];

        // (2) issue next-kstep global prefetch (stays in flight through MFMAs)
        if (ks < 3) stage_load(ks + 1);

        // (3) MFMA burst: x from LDS (lgkmcnt only), w from registers
        const unsigned short* lb = lds + buf * L_BUF;

        #define DO_TAP(t, dh, dw)                                                    \
            {                                                                        \
                f32x16 a = acc[dh][dw];                                              \
                a = __builtin_amdgcn_mfma_f32_32x32x16_f16(wr[t], xh, a, 0, 0, 0);   \
                a = __builtin_amdgcn_mfma_f32_32x32x16_f16(wr[t], xl, a, 0, 0, 0);   \
                acc[dh][dw] = a;                                                     \
            }
        #define LOAD_XF(r, s)                                                        \
            half8 xh, xl;                                                            \
            {                                                                        \
                int xo = (rp + (r)) * L_ROW + (jj + (s)) * L_JST + ch * 8;           \
                xh = *(const half8*)&lb[xo];                                         \
                xl = *(const half8*)&lb[xo + L_HL];                                  \
            }

        { LOAD_XF(1, 1) DO_TAP(0, 1, 1) }                                   // t0
        { LOAD_XF(1, 0) DO_TAP(1, 1, 0) DO_TAP(2, 1, 1) }                   // t1,t2
        { LOAD_XF(0, 1) DO_TAP(3, 0, 1) DO_TAP(6, 1, 1) }                   // t3,t6
        { LOAD_XF(0, 0) DO_TAP(4, 0, 0) DO_TAP(5, 0, 1)
                        DO_TAP(7, 1, 0) DO_TAP(8, 1, 1) }                   // t4,5,7,8
        #undef DO_TAP
        #undef LOAD_XF

        // (4) drain stage loads (vmcnt(0) here only), convert, write other buffer
        if (ks < 3) {
            stage_write(buf ^ 1);
            __syncthreads();
        }
    }

    // ---- epilogue: bias + clamp; lane = pixel -> coalesced dwordx2 stores ----
    float bco[16];
    #pragma unroll
    for (int rg = 0; rg < 16; ++rg)
        bco[rg] = bias[ct * 32 + (rg & 3) + 8 * (rg >> 2) + 4 * ch];

    float* outn = out + (size_t)n * COUT * HO * WO;
    const int ow0 = 2 * (j0 + jj);
    #pragma unroll
    for (int dh = 0; dh < 2; ++dh) {
        const int oh = 2 * (i_in + rp) + dh;
        #pragma unroll
        for (int rg = 0; rg < 16; ++rg) {
            const int co = ct * 32 + (rg & 3) + 8 * (rg >> 2) + 4 * ch;
            float v0 = acc[dh][0][rg] + bco[rg];
            float v1 = acc[dh][1][rg] + bco[rg];
            v0 = fminf(fmaxf(v0, 0.f), 0.5f);
            v1 = fminf(fmaxf(v1, 0.f), 0.5f);
            *(float2*)&outn[((size_t)co * HO + oh) * WO + ow0] = make_float2(v0, v1);
        }
    }
}

// ---------------- fallback (no-workspace): fp32 VALU kernel ----------------
#define TILE_I 4
#define TILE_J 16
#define HALO_I (TILE_I + 1)
#define HALO_J (TILE_J + 1)
#define XS_CSTRIDE 20
#define XS_RSTRIDE (HALO_I * XS_CSTRIDE)
#define XS_FLOATS (CIN * XS_RSTRIDE)

struct Regs { float wk[9]; float xa[2][HALO_J]; };

__device__ __forceinline__ void load_ci_fb(int ci, const float* __restrict__ wsrc,
                                           const float* xs, int warp, int lane, Regs& R) {
    #pragma unroll
    for (int k = 0; k < 9; ++k) R.wk[k] = wsrc[(ci * COUT + lane) * 9 + k];
    const float* xr = xs + ci * XS_RSTRIDE + warp * XS_CSTRIDE;
    #pragma unroll
    for (int rr = 0; rr < 2; ++rr) {
        const float4* p4 = reinterpret_cast<const float4*>(xr + rr * XS_CSTRIDE);
        #pragma unroll
        for (int q = 0; q < 4; ++q) {
            float4 v = p4[q];
            R.xa[rr][4*q+0] = v.x; R.xa[rr][4*q+1] = v.y;
            R.xa[rr][4*q+2] = v.z; R.xa[rr][4*q+3] = v.w;
        }
        R.xa[rr][16] = xr[rr * XS_CSTRIDE + 16];
    }
}

__device__ __forceinline__ void do_fma_fb(const Regs& R, float (&acc)[TILE_J][4]) {
    #pragma unroll
    for (int p = 0; p < TILE_J; ++p) {
        const float x00 = R.xa[0][p], x01 = R.xa[0][p+1];
        const float x10 = R.xa[1][p], x11 = R.xa[1][p+1];
        acc[p][0] += x00 * R.wk[4];
        acc[p][1] += x00 * R.wk[5]; acc[p][1] += x01 * R.wk[3];
        acc[p][2] += x00 * R.wk[7]; acc[p][2] += x10 * R.wk[1];
        acc[p][3] += x00 * R.wk[8]; acc[p][3] += x01 * R.wk[6];
        acc[p][3] += x10 * R.wk[2]; acc[p][3] += x11 * R.wk[0];
    }
}

__device__ __forceinline__ int es_slot_fb(int co, int oh, int g) {
    return co * 64 + oh * 8 + (g ^ (co & 7) ^ oh);
}

__global__ __launch_bounds__(256, 2) void convt_fallback_kernel(
    const float* __restrict__ x, const float* __restrict__ wsrc,
    const float* __restrict__ bias, float* __restrict__ out) {
    __shared__ __align__(16) float xs[XS_FLOATS];
    const int n = blockIdx.z, i0 = blockIdx.y * TILE_I, j0 = blockIdx.x * TILE_J;
    const float* xnf = x + (size_t)n * CIN * HI * WI;
    for (int f = threadIdx.x; f < CIN * HALO_I * HALO_J; f += 256) {
        int ci = f / (HALO_I * HALO_J);
        int rem = f - ci * (HALO_I * HALO_J);
        int r = rem / HALO_J, c = rem - r * HALO_J;
        int gi = i0 + r, gj = j0 + c;
        float v = 0.0f;
        if (gi < HI && gj < WI) v = xnf[(ci * HI + gi) * WI + gj];
        xs[ci * XS_RSTRIDE + r * XS_CSTRIDE + c] = v;
    }
    __syncthreads();
    const int warp = threadIdx.x >> 6, lane = threadIdx.x & 63;
    const float bcf = bias[lane];
    float acc[TILE_J][4];
    #pragma unroll
    for (int p = 0; p < TILE_J; ++p)
        #pragma unroll
        for (int q = 0; q < 4; ++q) acc[p][q] = 0.0f;
    Regs A, B1;
    load_ci_fb(0, wsrc, xs, warp, lane, A);
    #pragma unroll 1
    for (int ci = 0; ci < CIN; ci += 2) {
        load_ci_fb(ci + 1, wsrc, xs, warp, lane, B1);
        do_fma_fb(A, acc);
        int cin = (ci + 2 < CIN) ? ci + 2 : CIN - 1;
        load_ci_fb(cin, wsrc, xs, warp, lane, A);
        do_fma_fb(B1, acc);
    }
    float* outn = out + (size_t)n * COUT * HO * WO;
    const int ohb = 2 * i0, owb = 2 * j0;
    __syncthreads();
    float* es = xs;
    #pragma unroll 1
    for (int chunk = 0; chunk < 4; ++chunk) {
        const int c0 = chunk * 16;
        if ((lane & 48) == c0) {
            const int col = lane & 15;
            #pragma unroll
            for (int p = 0; p < TILE_J; ++p)
                #pragma unroll
                for (int q = 0; q < 4; ++q) {
                    const int ohl = warp * 2 + (q >> 1);
                    const int ow = 2 * p + (q & 1);
                    float v = acc[p][q] + bcf;
                    v = fminf(fmaxf(v, 0.0f), 0.5f);
                    es[es_slot_fb(col, ohl, ow >> 2) * 4 + (ow & 3)] = v;
                }
        }
        __syncthreads();
        {
            const int co_l = threadIdx.x >> 4;
            const int oh_l = (threadIdx.x & 15) >> 1;
            const int half = threadIdx.x & 1;
            float* dst = &outn[((size_t)(c0 + co_l) * HO + (ohb + oh_l)) * WO + owb + half * 16];
            #pragma unroll
            for (int qq = 0; qq < 4; ++qq) {
                const int g = half * 4 + qq;
                float4 v = *reinterpret_cast<const float4*>(&es[es_slot_fb(co_l, oh_l, g) * 4]);
                *reinterpret_cast<float4*>(dst + qq * 4) = v;
            }
        }
        __syncthreads();
    }
}

extern "C" void kernel_launch(void* const* d_in, const int* in_sizes, int n_in,
                              void* d_out, int out_size, void* d_ws, size_t ws_size,
                              hipStream_t stream) {
    const float* x = (const float*)d_in[0];
    const float* w = (const float*)d_in[1];
    const float* b = (const float*)d_in[2];
    float* out = (float*)d_out;
    const int B = in_sizes[0] / (CIN * HI * WI);  // 32

    const size_t wf_bytes = (size_t)72 * 64 * 8 * sizeof(unsigned short); // 73728
    if (ws_size >= wf_bytes) {
        unsigned short* wfrag = (unsigned short*)d_ws;
        prep_wfrag<<<18, 256, 0, stream>>>(w, wfrag);
        dim3 grid(WI / 32, HI / 2, B);            // (4, 64, 32)
        convt_mfma_kernel<<<grid, 256, 0, stream>>>(x, wfrag, b, out);
    } else {
        dim3 grid(WI / TILE_J, HI / TILE_I, B);   // (8, 32, 32)
        convt_fallback_kernel<<<grid, 256, 0, stream>>>(x, w, b, out);
    }
}